// Round 1
// baseline (412.716 us; speedup 1.0000x reference)
//
#include <hip/hip_runtime.h>

typedef __bf16 bf16x8 __attribute__((ext_vector_type(8)));
typedef float f32x4 __attribute__((ext_vector_type(4)));

// ---------------------------------------------------------------------------
// Weight prep: W [K][N] fp32 -> Wt [N][K] bf16  (K-contiguous for MFMA B-frag)
// ---------------------------------------------------------------------------
__global__ void wt_transpose_kernel(const float* __restrict__ W,
                                    __bf16* __restrict__ Wt, int K, int N) {
    int n = blockIdx.x;
    for (int k = threadIdx.x; k < K; k += blockDim.x) {
        Wt[(size_t)n * K + k] = (__bf16)W[(size_t)k * N + n];
    }
}

// ---------------------------------------------------------------------------
// LayerNorm: one block per row, fp32 in -> bf16 out.  D % 2048-friendly
// (needs D % 8 == 0; block = 256 threads, 8 elems/thread/iter)
// ---------------------------------------------------------------------------
__global__ __launch_bounds__(256) void ln_kernel(const float* __restrict__ x,
                                                 const float* __restrict__ g,
                                                 const float* __restrict__ be,
                                                 __bf16* __restrict__ y, int D) {
    const int t = threadIdx.x;
    const size_t row = blockIdx.x;
    const float4* xr = (const float4*)(x + row * (size_t)D);
    const int nv = D >> 3;  // number of 8-elem groups
    float s = 0.f, ss = 0.f;
    for (int i = t; i < nv; i += 256) {
        float4 v0 = xr[i * 2], v1 = xr[i * 2 + 1];
        s += v0.x + v0.y + v0.z + v0.w + v1.x + v1.y + v1.z + v1.w;
        ss += v0.x * v0.x + v0.y * v0.y + v0.z * v0.z + v0.w * v0.w +
              v1.x * v1.x + v1.y * v1.y + v1.z * v1.z + v1.w * v1.w;
    }
    // wave (64-lane) reduce, then cross-wave via LDS
    for (int o = 32; o > 0; o >>= 1) {
        s += __shfl_down(s, o);
        ss += __shfl_down(ss, o);
    }
    __shared__ float ps[4], pss[4], mv[2];
    int w = t >> 6;
    if ((t & 63) == 0) { ps[w] = s; pss[w] = ss; }
    __syncthreads();
    if (t == 0) {
        float S = ps[0] + ps[1] + ps[2] + ps[3];
        float SS = pss[0] + pss[1] + pss[2] + pss[3];
        float mu = S / (float)D;
        float var = SS / (float)D - mu * mu;
        mv[0] = mu;
        mv[1] = rsqrtf(var + 1e-5f);
    }
    __syncthreads();
    float mu = mv[0], rstd = mv[1];
    const float4* gg = (const float4*)g;
    const float4* bb = (const float4*)be;
    bf16x8* yr = (bf16x8*)(y + row * (size_t)D);
    for (int i = t; i < nv; i += 256) {
        float4 v0 = xr[i * 2], v1 = xr[i * 2 + 1];
        float4 g0 = gg[i * 2], g1 = gg[i * 2 + 1];
        float4 b0 = bb[i * 2], b1 = bb[i * 2 + 1];
        bf16x8 o;
        o[0] = (__bf16)((v0.x - mu) * rstd * g0.x + b0.x);
        o[1] = (__bf16)((v0.y - mu) * rstd * g0.y + b0.y);
        o[2] = (__bf16)((v0.z - mu) * rstd * g0.z + b0.z);
        o[3] = (__bf16)((v0.w - mu) * rstd * g0.w + b0.w);
        o[4] = (__bf16)((v1.x - mu) * rstd * g1.x + b1.x);
        o[5] = (__bf16)((v1.y - mu) * rstd * g1.y + b1.y);
        o[6] = (__bf16)((v1.z - mu) * rstd * g1.z + b1.z);
        o[7] = (__bf16)((v1.w - mu) * rstd * g1.w + b1.w);
        yr[i] = o;
    }
}

// ---------------------------------------------------------------------------
// bf16 MFMA GEMM, m97-style 128x128 tile, BK=32, global_load_lds width=16.
// A: [M][K] bf16 row-major; Bt: [N][K] bf16 row-major (i.e. B transposed).
// EPI 0: out = silu(acc + bias) -> bf16 Cout
// EPI 1: out = hid + alpha*(acc + bias - hid) -> fp32 Cout
// Requires M%128==0, N%128==0, K%32==0.
// ---------------------------------------------------------------------------
template <int EPI>
__global__ __launch_bounds__(256) void gemm_bt(const __bf16* __restrict__ A,
                                               const __bf16* __restrict__ Bt,
                                               const float* __restrict__ bias,
                                               const float* __restrict__ hid,
                                               const float* __restrict__ alpha_p,
                                               void* __restrict__ Cout,
                                               int M, int N, int K) {
    constexpr int BM = 128, BN = 128, BK = 32;
    __shared__ __align__(16) __bf16 Ads[BM * BK];
    __shared__ __align__(16) __bf16 Bds[BN * BK];

    const int tid = threadIdx.x;
    const int wave = tid >> 6;
    const int lane = tid & 63;
    const int bn = blockIdx.x, bm = blockIdx.y;
    const int row0 = bm * BM, col0 = bn * BN;
    const int wr = wave >> 1, wc = wave & 1;  // 2x2 wave grid, 64x64 per wave

    f32x4 acc[4][4] = {};

    const __bf16* Ag = A + (size_t)row0 * K;
    const __bf16* Bg = Bt + (size_t)col0 * K;
    const int lrow = lane >> 2;       // 0..15: row within 16-row group
    const int lk = (lane & 3) * 8;    // 0,8,16,24: k-offset (8 bf16 = 16 B)

    const int c = lane & 15;  // fragment m/n/col index
    const int q = lane >> 4;  // quad

    for (int k0 = 0; k0 < K; k0 += BK) {
#pragma unroll
        for (int p = 0; p < 2; ++p) {
            int r = wave * 32 + p * 16;  // wave-uniform 16-row group base
            __builtin_amdgcn_global_load_lds(
                (__attribute__((address_space(1))) void*)(Ag + (size_t)(r + lrow) * K + k0 + lk),
                (__attribute__((address_space(3))) void*)(Ads + r * BK),
                16, 0, 0);
            __builtin_amdgcn_global_load_lds(
                (__attribute__((address_space(1))) void*)(Bg + (size_t)(r + lrow) * K + k0 + lk),
                (__attribute__((address_space(3))) void*)(Bds + r * BK),
                16, 0, 0);
        }
        __syncthreads();  // implies vmcnt(0): global_load_lds complete

        bf16x8 af[4], bfr[4];
#pragma unroll
        for (int i = 0; i < 4; ++i)
            af[i] = *(const bf16x8*)(Ads + (wr * 64 + i * 16 + c) * BK + q * 8);
#pragma unroll
        for (int j = 0; j < 4; ++j)
            bfr[j] = *(const bf16x8*)(Bds + (wc * 64 + j * 16 + c) * BK + q * 8);
#pragma unroll
        for (int i = 0; i < 4; ++i)
#pragma unroll
            for (int j = 0; j < 4; ++j)
                acc[i][j] = __builtin_amdgcn_mfma_f32_16x16x32_bf16(af[i], bfr[j],
                                                                    acc[i][j], 0, 0, 0);
        __syncthreads();
    }

    // Epilogue.  C/D layout: col = lane&15, row = quad*4 + reg  [m89/m91]
    float alpha = (EPI == 1) ? *alpha_p : 0.f;
#pragma unroll
    for (int i = 0; i < 4; ++i) {
#pragma unroll
        for (int j = 0; j < 4; ++j) {
            int colg = col0 + wc * 64 + j * 16 + c;
            float bv = bias[colg];
#pragma unroll
            for (int r = 0; r < 4; ++r) {
                int rowg = row0 + wr * 64 + i * 16 + q * 4 + r;
                size_t idx = (size_t)rowg * N + colg;
                float v = acc[i][j][r] + bv;
                if (EPI == 0) {
                    float sv = v / (1.f + __expf(-v));
                    ((__bf16*)Cout)[idx] = (__bf16)sv;
                } else {
                    float h = hid[idx];
                    ((float*)Cout)[idx] = h + alpha * (v - h);
                }
            }
        }
    }
}

// ---------------------------------------------------------------------------
// Launch
// ---------------------------------------------------------------------------
extern "C" void kernel_launch(void* const* d_in, const int* in_sizes, int n_in,
                              void* d_out, int out_size, void* d_ws, size_t ws_size,
                              hipStream_t stream) {
    const float* hidden = (const float*)d_in[0];
    const float* ln_gamma = (const float*)d_in[1];
    const float* ln_beta = (const float*)d_in[2];
    const float* W_down = (const float*)d_in[3];
    const float* b_down = (const float*)d_in[4];
    const float* W_up = (const float*)d_in[5];
    const float* b_up = (const float*)d_in[6];
    const float* alpha = (const float*)d_in[7];
    float* out = (float*)d_out;

    const int D = in_sizes[2];            // 2048 (ln_beta)
    const int Db = in_sizes[4];           // 512  (b_down)
    const int M = in_sizes[0] / D;        // 16384 (B*S)

    // workspace carve-up
    char* w = (char*)d_ws;
    __bf16* hn = (__bf16*)w;   w += (size_t)M * D * sizeof(__bf16);
    __bf16* z = (__bf16*)w;    w += (size_t)M * Db * sizeof(__bf16);
    __bf16* Wtd = (__bf16*)w;  w += (size_t)D * Db * sizeof(__bf16);  // [Db][D]
    __bf16* Wtu = (__bf16*)w;  w += (size_t)Db * D * sizeof(__bf16);  // [D][Db]

    // 1) weights -> bf16, transposed to [N][K]
    wt_transpose_kernel<<<Db, 256, 0, stream>>>(W_down, Wtd, D, Db);
    wt_transpose_kernel<<<D, 256, 0, stream>>>(W_up, Wtu, Db, D);

    // 2) LayerNorm -> bf16 h_norm
    ln_kernel<<<M, 256, 0, stream>>>(hidden, ln_gamma, ln_beta, hn, D);

    // 3) GEMM1: z = silu(h_norm @ W_down + b_down)   [M][Db] bf16
    gemm_bt<0><<<dim3(Db / 128, M / 128), 256, 0, stream>>>(
        hn, Wtd, b_down, nullptr, nullptr, (void*)z, M, Db, D);

    // 4) GEMM2 + residual: out = hidden + alpha*((z @ W_up + b_up) - hidden)
    gemm_bt<1><<<dim3(D / 128, M / 128), 256, 0, stream>>>(
        z, Wtu, b_up, hidden, alpha, (void*)out, M, D, Db);
}

// Round 2
// 395.253 us; speedup vs baseline: 1.0442x; 1.0442x over previous
//
#include <hip/hip_runtime.h>

typedef __bf16 bf16x8 __attribute__((ext_vector_type(8)));
typedef __bf16 bf16x4 __attribute__((ext_vector_type(4)));
typedef float f32x4 __attribute__((ext_vector_type(4)));

// ---------------------------------------------------------------------------
// Weight prep (single dispatch): W [K][N] fp32 -> Wt [N][K] bf16, LDS-tiled
// 32x32 transpose so both global read and write are coalesced.
// ---------------------------------------------------------------------------
__global__ __launch_bounds__(256) void prep_kernel(const float* __restrict__ Wd,
                                                   __bf16* __restrict__ Wtd,
                                                   const float* __restrict__ Wu,
                                                   __bf16* __restrict__ Wtu,
                                                   int D, int Db) {
    const float* W;
    __bf16* Wt;
    int K, N, tile;
    const int ntile_d = (Db / 32) * (D / 32);
    if ((int)blockIdx.x < ntile_d) {
        W = Wd; Wt = Wtd; K = D; N = Db; tile = blockIdx.x;
    } else {
        W = Wu; Wt = Wtu; K = Db; N = D; tile = blockIdx.x - ntile_d;
    }
    const int tn = tile % (N / 32), tk = tile / (N / 32);
    const int n0 = tn * 32, k0 = tk * 32;
    __shared__ float t[32][33];
    const int c = threadIdx.x & 31, r0 = threadIdx.x >> 5;  // 8 rows/pass
#pragma unroll
    for (int r = r0; r < 32; r += 8)
        t[r][c] = W[(size_t)(k0 + r) * N + n0 + c];
    __syncthreads();
#pragma unroll
    for (int r = r0; r < 32; r += 8)
        Wt[(size_t)(n0 + r) * K + k0 + c] = (__bf16)t[c][r];
}

// ---------------------------------------------------------------------------
// LayerNorm: one block per row, fp32 in -> bf16 out.
// ---------------------------------------------------------------------------
__global__ __launch_bounds__(256) void ln_kernel(const float* __restrict__ x,
                                                 const float* __restrict__ g,
                                                 const float* __restrict__ be,
                                                 __bf16* __restrict__ y, int D) {
    const int t = threadIdx.x;
    const size_t row = blockIdx.x;
    const float4* xr = (const float4*)(x + row * (size_t)D);
    const int nv = D >> 3;
    float s = 0.f, ss = 0.f;
    for (int i = t; i < nv; i += 256) {
        float4 v0 = xr[i * 2], v1 = xr[i * 2 + 1];
        s += v0.x + v0.y + v0.z + v0.w + v1.x + v1.y + v1.z + v1.w;
        ss += v0.x * v0.x + v0.y * v0.y + v0.z * v0.z + v0.w * v0.w +
              v1.x * v1.x + v1.y * v1.y + v1.z * v1.z + v1.w * v1.w;
    }
    for (int o = 32; o > 0; o >>= 1) {
        s += __shfl_down(s, o);
        ss += __shfl_down(ss, o);
    }
    __shared__ float ps[4], pss[4], mv[2];
    int w = t >> 6;
    if ((t & 63) == 0) { ps[w] = s; pss[w] = ss; }
    __syncthreads();
    if (t == 0) {
        float S = ps[0] + ps[1] + ps[2] + ps[3];
        float SS = pss[0] + pss[1] + pss[2] + pss[3];
        float mu = S / (float)D;
        float var = SS / (float)D - mu * mu;
        mv[0] = mu;
        mv[1] = rsqrtf(var + 1e-5f);
    }
    __syncthreads();
    float mu = mv[0], rstd = mv[1];
    const float4* gg = (const float4*)g;
    const float4* bb = (const float4*)be;
    bf16x8* yr = (bf16x8*)(y + row * (size_t)D);
    for (int i = t; i < nv; i += 256) {
        float4 v0 = xr[i * 2], v1 = xr[i * 2 + 1];
        float4 g0 = gg[i * 2], g1 = gg[i * 2 + 1];
        float4 b0 = bb[i * 2], b1 = bb[i * 2 + 1];
        bf16x8 o;
        o[0] = (__bf16)((v0.x - mu) * rstd * g0.x + b0.x);
        o[1] = (__bf16)((v0.y - mu) * rstd * g0.y + b0.y);
        o[2] = (__bf16)((v0.z - mu) * rstd * g0.z + b0.z);
        o[3] = (__bf16)((v0.w - mu) * rstd * g0.w + b0.w);
        o[4] = (__bf16)((v1.x - mu) * rstd * g1.x + b1.x);
        o[5] = (__bf16)((v1.y - mu) * rstd * g1.y + b1.y);
        o[6] = (__bf16)((v1.z - mu) * rstd * g1.z + b1.z);
        o[7] = (__bf16)((v1.w - mu) * rstd * g1.w + b1.w);
        yr[i] = o;
    }
}

// ---------------------------------------------------------------------------
// bf16 MFMA GEMM, 128x128 tile, BK=32, global_load_lds width=16.
// OPERAND-SWAP: we call mfma(W_frag, act_frag, acc) so the D layout comes out
// transposed: lane (c=lane&15, q=lane>>4) reg r  <->  out[row=c][col=q*4+r].
// Each lane's 4 acc regs are 4 CONSECUTIVE output columns -> float4 epilogue.
// A: activations [M][K] bf16 row-major; Bt: weights [N][K] bf16 row-major.
// EPI 0: out = silu(acc + bias) -> bf16 Cout          (8 B stores)
// EPI 1: out = hid + alpha*(acc + bias - hid) -> fp32 (16 B loads+stores)
// Requires M%128==0, N%128==0, K%32==0.
// ---------------------------------------------------------------------------
template <int EPI>
__global__ __launch_bounds__(256) void gemm_bt(const __bf16* __restrict__ A,
                                               const __bf16* __restrict__ Bt,
                                               const float* __restrict__ bias,
                                               const float* __restrict__ hid,
                                               const float* __restrict__ alpha_p,
                                               void* __restrict__ Cout,
                                               int M, int N, int K) {
    constexpr int BM = 128, BN = 128, BK = 32;
    __shared__ __align__(16) __bf16 Ads[BM * BK];
    __shared__ __align__(16) __bf16 Bds[BN * BK];

    const int tid = threadIdx.x;
    const int wave = tid >> 6;
    const int lane = tid & 63;
    const int bn = blockIdx.x, bm = blockIdx.y;
    const int row0 = bm * BM, col0 = bn * BN;
    const int wr = wave >> 1, wc = wave & 1;  // 2x2 wave grid, 64x64 per wave

    f32x4 acc[4][4] = {};  // [i = act row-tile][j = W col-tile]

    const __bf16* Ag = A + (size_t)row0 * K;
    const __bf16* Bg = Bt + (size_t)col0 * K;
    const int lrow = lane >> 2;     // 0..15: row within 16-row group
    const int lk = (lane & 3) * 8;  // 0,8,16,24: k-offset (8 bf16 = 16 B)

    const int c = lane & 15;  // operand non-k index
    const int q = lane >> 4;  // quad

    for (int k0 = 0; k0 < K; k0 += BK) {
#pragma unroll
        for (int p = 0; p < 2; ++p) {
            int r = wave * 32 + p * 16;  // wave-uniform 16-row group base
            __builtin_amdgcn_global_load_lds(
                (__attribute__((address_space(1))) void*)(Ag + (size_t)(r + lrow) * K + k0 + lk),
                (__attribute__((address_space(3))) void*)(Ads + r * BK),
                16, 0, 0);
            __builtin_amdgcn_global_load_lds(
                (__attribute__((address_space(1))) void*)(Bg + (size_t)(r + lrow) * K + k0 + lk),
                (__attribute__((address_space(3))) void*)(Bds + r * BK),
                16, 0, 0);
        }
        __syncthreads();

        bf16x8 afW[4], bfA[4];
#pragma unroll
        for (int j = 0; j < 4; ++j)
            afW[j] = *(const bf16x8*)(Bds + (wc * 64 + j * 16 + c) * BK + q * 8);
#pragma unroll
        for (int i = 0; i < 4; ++i)
            bfA[i] = *(const bf16x8*)(Ads + (wr * 64 + i * 16 + c) * BK + q * 8);
#pragma unroll
        for (int i = 0; i < 4; ++i)
#pragma unroll
            for (int j = 0; j < 4; ++j)
                acc[i][j] = __builtin_amdgcn_mfma_f32_16x16x32_bf16(afW[j], bfA[i],
                                                                    acc[i][j], 0, 0, 0);
        __syncthreads();
    }

    // Epilogue (swapped-D layout): lane holds out[rowg][colb + 0..3]
    float alpha = (EPI == 1) ? *alpha_p : 0.f;
#pragma unroll
    for (int i = 0; i < 4; ++i) {
        const int rowg = row0 + wr * 64 + i * 16 + c;
#pragma unroll
        for (int j = 0; j < 4; ++j) {
            const int colb = col0 + wc * 64 + j * 16 + q * 4;
            const float4 bv = *(const float4*)(bias + colb);
            float v0 = acc[i][j][0] + bv.x;
            float v1 = acc[i][j][1] + bv.y;
            float v2 = acc[i][j][2] + bv.z;
            float v3 = acc[i][j][3] + bv.w;
            const size_t idx = (size_t)rowg * N + colb;
            if (EPI == 0) {
                bf16x4 o;
                o[0] = (__bf16)(v0 / (1.f + __expf(-v0)));
                o[1] = (__bf16)(v1 / (1.f + __expf(-v1)));
                o[2] = (__bf16)(v2 / (1.f + __expf(-v2)));
                o[3] = (__bf16)(v3 / (1.f + __expf(-v3)));
                *(bf16x4*)((__bf16*)Cout + idx) = o;
            } else {
                const float4 h = *(const float4*)(hid + idx);
                float4 o;
                o.x = h.x + alpha * (v0 - h.x);
                o.y = h.y + alpha * (v1 - h.y);
                o.z = h.z + alpha * (v2 - h.z);
                o.w = h.w + alpha * (v3 - h.w);
                *(float4*)((float*)Cout + idx) = o;
            }
        }
    }
}

// ---------------------------------------------------------------------------
// Launch
// ---------------------------------------------------------------------------
extern "C" void kernel_launch(void* const* d_in, const int* in_sizes, int n_in,
                              void* d_out, int out_size, void* d_ws, size_t ws_size,
                              hipStream_t stream) {
    const float* hidden = (const float*)d_in[0];
    const float* ln_gamma = (const float*)d_in[1];
    const float* ln_beta = (const float*)d_in[2];
    const float* W_down = (const float*)d_in[3];
    const float* b_down = (const float*)d_in[4];
    const float* W_up = (const float*)d_in[5];
    const float* b_up = (const float*)d_in[6];
    const float* alpha = (const float*)d_in[7];
    float* out = (float*)d_out;

    const int D = in_sizes[2];      // 2048
    const int Db = in_sizes[4];     // 512
    const int M = in_sizes[0] / D;  // 16384

    char* w = (char*)d_ws;
    __bf16* hn = (__bf16*)w;  w += (size_t)M * D * sizeof(__bf16);
    __bf16* z = (__bf16*)w;   w += (size_t)M * Db * sizeof(__bf16);
    __bf16* Wtd = (__bf16*)w; w += (size_t)D * Db * sizeof(__bf16);  // [Db][D]
    __bf16* Wtu = (__bf16*)w; w += (size_t)Db * D * sizeof(__bf16);  // [D][Db]

    const int ntiles = 2 * (D / 32) * (Db / 32);
    prep_kernel<<<ntiles, 256, 0, stream>>>(W_down, Wtd, W_up, Wtu, D, Db);

    ln_kernel<<<M, 256, 0, stream>>>(hidden, ln_gamma, ln_beta, hn, D);

    gemm_bt<0><<<dim3(Db / 128, M / 128), 256, 0, stream>>>(
        hn, Wtd, b_down, nullptr, nullptr, (void*)z, M, Db, D);

    gemm_bt<1><<<dim3(D / 128, M / 128), 256, 0, stream>>>(
        z, Wtu, b_up, hidden, alpha, (void*)out, M, D, Db);
}

// Round 3
// 394.338 us; speedup vs baseline: 1.0466x; 1.0023x over previous
//
#include <hip/hip_runtime.h>

typedef __bf16 bf16x8 __attribute__((ext_vector_type(8)));
typedef __bf16 bf16x4 __attribute__((ext_vector_type(4)));
typedef float f32x4 __attribute__((ext_vector_type(4)));

#define S_BARRIER() asm volatile("s_barrier" ::: "memory")
#define WAITCNT_VM(n) asm volatile("s_waitcnt vmcnt(" #n ")" ::: "memory")
#define WAITCNT_LGKM0() asm volatile("s_waitcnt lgkmcnt(0)" ::: "memory")

// ---------------------------------------------------------------------------
// Fused prep (weight transpose+cast) + LayerNorm, one dispatch.
// Blocks [0, ntiles): 32x32 LDS-tiled transpose of W_down / W_up -> bf16 [N][K]
// Blocks [ntiles, ntiles+M): LayerNorm row -> bf16
// ---------------------------------------------------------------------------
__global__ __launch_bounds__(256) void prep_ln_kernel(
    const float* __restrict__ Wd, __bf16* __restrict__ Wtd,
    const float* __restrict__ Wu, __bf16* __restrict__ Wtu,
    const float* __restrict__ x, const float* __restrict__ g,
    const float* __restrict__ be, __bf16* __restrict__ y,
    int D, int Db, int ntiles) {
    if ((int)blockIdx.x < ntiles) {
        // ---- weight transpose ----
        const float* W;
        __bf16* Wt;
        int K, N, tile;
        const int ntile_d = (Db / 32) * (D / 32);
        if ((int)blockIdx.x < ntile_d) {
            W = Wd; Wt = Wtd; K = D; N = Db; tile = blockIdx.x;
        } else {
            W = Wu; Wt = Wtu; K = Db; N = D; tile = blockIdx.x - ntile_d;
        }
        const int tn = tile % (N / 32), tk = tile / (N / 32);
        const int n0 = tn * 32, k0 = tk * 32;
        __shared__ float t[32][33];
        const int c = threadIdx.x & 31, r0 = threadIdx.x >> 5;
#pragma unroll
        for (int r = r0; r < 32; r += 8)
            t[r][c] = W[(size_t)(k0 + r) * N + n0 + c];
        __syncthreads();
#pragma unroll
        for (int r = r0; r < 32; r += 8)
            Wt[(size_t)(n0 + r) * K + k0 + c] = (__bf16)t[c][r];
        return;
    }
    // ---- LayerNorm ----
    const int t = threadIdx.x;
    const size_t row = blockIdx.x - ntiles;
    const float4* xr = (const float4*)(x + row * (size_t)D);
    const int nv = D >> 3;
    float s = 0.f, ss = 0.f;
    for (int i = t; i < nv; i += 256) {
        float4 v0 = xr[i * 2], v1 = xr[i * 2 + 1];
        s += v0.x + v0.y + v0.z + v0.w + v1.x + v1.y + v1.z + v1.w;
        ss += v0.x * v0.x + v0.y * v0.y + v0.z * v0.z + v0.w * v0.w +
              v1.x * v1.x + v1.y * v1.y + v1.z * v1.z + v1.w * v1.w;
    }
    for (int o = 32; o > 0; o >>= 1) {
        s += __shfl_down(s, o);
        ss += __shfl_down(ss, o);
    }
    __shared__ float ps[4], pss[4], mv[2];
    int w = t >> 6;
    if ((t & 63) == 0) { ps[w] = s; pss[w] = ss; }
    __syncthreads();
    if (t == 0) {
        float S = ps[0] + ps[1] + ps[2] + ps[3];
        float SS = pss[0] + pss[1] + pss[2] + pss[3];
        float mu = S / (float)D;
        float var = SS / (float)D - mu * mu;
        mv[0] = mu;
        mv[1] = rsqrtf(var + 1e-5f);
    }
    __syncthreads();
    float mu = mv[0], rstd = mv[1];
    const float4* gg = (const float4*)g;
    const float4* bb = (const float4*)be;
    bf16x8* yr = (bf16x8*)(y + row * (size_t)D);
    for (int i = t; i < nv; i += 256) {
        float4 v0 = xr[i * 2], v1 = xr[i * 2 + 1];
        float4 g0 = gg[i * 2], g1 = gg[i * 2 + 1];
        float4 b0 = bb[i * 2], b1 = bb[i * 2 + 1];
        bf16x8 o;
        o[0] = (__bf16)((v0.x - mu) * rstd * g0.x + b0.x);
        o[1] = (__bf16)((v0.y - mu) * rstd * g0.y + b0.y);
        o[2] = (__bf16)((v0.z - mu) * rstd * g0.z + b0.z);
        o[3] = (__bf16)((v0.w - mu) * rstd * g0.w + b0.w);
        o[4] = (__bf16)((v1.x - mu) * rstd * g1.x + b1.x);
        o[5] = (__bf16)((v1.y - mu) * rstd * g1.y + b1.y);
        o[6] = (__bf16)((v1.z - mu) * rstd * g1.z + b1.z);
        o[7] = (__bf16)((v1.w - mu) * rstd * g1.w + b1.w);
        yr[i] = o;
    }
}

// ---------------------------------------------------------------------------
// Pipelined bf16 MFMA GEMM, 128x128 tile, BK=32, double-buffered LDS.
// - global_load_lds width=16 prefetches tile k+1 BEFORE waiting on tile k;
//   raw s_barrier + s_waitcnt vmcnt(4) keeps the 4 newest DMAs in flight
//   across the barrier (vmcnt is per-wave FIFO: <=4 outstanding => my 4
//   current-tile DMAs have landed; barrier => everyone's landed).
// - XOR bank swizzle: lane fetches k-chunk (lane&3)^(lrow&3) so LDS rows are
//   chunk-permuted; readers XOR with q^(row&3). Breaks the 8-way conflict of
//   the 64 B row stride (2-way max = free).
// - OPERAND-SWAP mfma(W,act,acc): lane (c,q) reg r <-> out[row=c][col=q*4+r],
//   4 consecutive output columns per lane -> float4 epilogue.
// A: activations [M][K] bf16; Bt: weights [N][K] bf16.
// EPI 0: out = silu(acc + bias) -> bf16.  EPI 1: residual -> fp32.
// ---------------------------------------------------------------------------
template <int EPI>
__global__ __launch_bounds__(256, 4) void gemm_bt(const __bf16* __restrict__ A,
                                                  const __bf16* __restrict__ Bt,
                                                  const float* __restrict__ bias,
                                                  const float* __restrict__ hid,
                                                  const float* __restrict__ alpha_p,
                                                  void* __restrict__ Cout,
                                                  int M, int N, int K) {
    constexpr int BM = 128, BN = 128, BK = 32;
    __shared__ __align__(16) __bf16 Ads[2][BM * BK];
    __shared__ __align__(16) __bf16 Bds[2][BN * BK];

    const int tid = threadIdx.x;
    const int wave = tid >> 6;
    const int lane = tid & 63;
    const int bn = blockIdx.x, bm = blockIdx.y;
    const int row0 = bm * BM, col0 = bn * BN;
    const int wr = wave >> 1, wc = wave & 1;  // 2x2 wave grid, 64x64 per wave

    f32x4 acc[4][4] = {};

    const __bf16* Ag = A + (size_t)row0 * K;
    const __bf16* Bg = Bt + (size_t)col0 * K;
    const int lrow = lane >> 2;                        // 0..15 within 16-row group
    const int lk = ((lane & 3) ^ (lrow & 3)) * 8;      // swizzled k-chunk (elements)

    const int c = lane & 15;  // operand non-k index
    const int q = lane >> 4;  // quad

    auto stage = [&](int k0, int b) {
#pragma unroll
        for (int p = 0; p < 2; ++p) {
            const int r = wave * 32 + p * 16;  // wave-uniform 16-row group base
            __builtin_amdgcn_global_load_lds(
                (__attribute__((address_space(1))) void*)(Ag + (size_t)(r + lrow) * K + k0 + lk),
                (__attribute__((address_space(3))) void*)(&Ads[b][r * BK]),
                16, 0, 0);
            __builtin_amdgcn_global_load_lds(
                (__attribute__((address_space(1))) void*)(Bg + (size_t)(r + lrow) * K + k0 + lk),
                (__attribute__((address_space(3))) void*)(&Bds[b][r * BK]),
                16, 0, 0);
        }
    };

    const int nk = K / BK;
    stage(0, 0);
    for (int it = 0; it < nk; ++it) {
        const int cur = it & 1;
        if (it + 1 < nk) {
            stage((it + 1) * BK, cur ^ 1);
            WAITCNT_VM(4);  // my 4 current-tile DMAs done; prefetch stays in flight
        } else {
            WAITCNT_VM(0);
        }
        S_BARRIER();  // everyone's current-tile DMAs landed

        bf16x8 afW[4], bfA[4];
#pragma unroll
        for (int j = 0; j < 4; ++j) {
            const int rl = wc * 64 + j * 16 + c;
            afW[j] = *(const bf16x8*)(&Bds[cur][rl * BK + ((q ^ (c & 3)) * 8)]);
        }
#pragma unroll
        for (int i = 0; i < 4; ++i) {
            const int rl = wr * 64 + i * 16 + c;
            bfA[i] = *(const bf16x8*)(&Ads[cur][rl * BK + ((q ^ (c & 3)) * 8)]);
        }
#pragma unroll
        for (int i = 0; i < 4; ++i)
#pragma unroll
            for (int j = 0; j < 4; ++j)
                acc[i][j] = __builtin_amdgcn_mfma_f32_16x16x32_bf16(afW[j], bfA[i],
                                                                    acc[i][j], 0, 0, 0);
        WAITCNT_LGKM0();  // my LDS reads retired
        S_BARRIER();      // buffer `cur` safe to overwrite next iteration
    }

    // Epilogue (swapped-D layout): lane holds out[rowg][colb + 0..3]
    float alpha = (EPI == 1) ? *alpha_p : 0.f;
#pragma unroll
    for (int i = 0; i < 4; ++i) {
        const int rowg = row0 + wr * 64 + i * 16 + c;
#pragma unroll
        for (int j = 0; j < 4; ++j) {
            const int colb = col0 + wc * 64 + j * 16 + q * 4;
            const float4 bv = *(const float4*)(bias + colb);
            float v0 = acc[i][j][0] + bv.x;
            float v1 = acc[i][j][1] + bv.y;
            float v2 = acc[i][j][2] + bv.z;
            float v3 = acc[i][j][3] + bv.w;
            const size_t idx = (size_t)rowg * N + colb;
            if (EPI == 0) {
                bf16x4 o;
                o[0] = (__bf16)(v0 / (1.f + __expf(-v0)));
                o[1] = (__bf16)(v1 / (1.f + __expf(-v1)));
                o[2] = (__bf16)(v2 / (1.f + __expf(-v2)));
                o[3] = (__bf16)(v3 / (1.f + __expf(-v3)));
                *(bf16x4*)((__bf16*)Cout + idx) = o;
            } else {
                const float4 h = *(const float4*)(hid + idx);
                float4 o;
                o.x = h.x + alpha * (v0 - h.x);
                o.y = h.y + alpha * (v1 - h.y);
                o.z = h.z + alpha * (v2 - h.z);
                o.w = h.w + alpha * (v3 - h.w);
                *(float4*)((float*)Cout + idx) = o;
            }
        }
    }
}

// ---------------------------------------------------------------------------
// Launch
// ---------------------------------------------------------------------------
extern "C" void kernel_launch(void* const* d_in, const int* in_sizes, int n_in,
                              void* d_out, int out_size, void* d_ws, size_t ws_size,
                              hipStream_t stream) {
    const float* hidden = (const float*)d_in[0];
    const float* ln_gamma = (const float*)d_in[1];
    const float* ln_beta = (const float*)d_in[2];
    const float* W_down = (const float*)d_in[3];
    const float* b_down = (const float*)d_in[4];
    const float* W_up = (const float*)d_in[5];
    const float* b_up = (const float*)d_in[6];
    const float* alpha = (const float*)d_in[7];
    float* out = (float*)d_out;

    const int D = in_sizes[2];      // 2048
    const int Db = in_sizes[4];     // 512
    const int M = in_sizes[0] / D;  // 16384

    char* w = (char*)d_ws;
    __bf16* hn = (__bf16*)w;  w += (size_t)M * D * sizeof(__bf16);
    __bf16* z = (__bf16*)w;   w += (size_t)M * Db * sizeof(__bf16);
    __bf16* Wtd = (__bf16*)w; w += (size_t)D * Db * sizeof(__bf16);  // [Db][D]
    __bf16* Wtu = (__bf16*)w; w += (size_t)Db * D * sizeof(__bf16);  // [D][Db]

    const int ntiles = 2 * (D / 32) * (Db / 32);
    prep_ln_kernel<<<ntiles + M, 256, 0, stream>>>(W_down, Wtd, W_up, Wtu,
                                                   hidden, ln_gamma, ln_beta, hn,
                                                   D, Db, ntiles);

    gemm_bt<0><<<dim3(Db / 128, M / 128), 256, 0, stream>>>(
        hn, Wtd, b_down, nullptr, nullptr, (void*)z, M, Db, D);

    gemm_bt<1><<<dim3(D / 128, M / 128), 256, 0, stream>>>(
        z, Wtu, b_up, hidden, alpha, (void*)out, M, D, Db);
}